// Round 8
// baseline (452.201 us; speedup 1.0000x reference)
//
#include <hip/hip_runtime.h>
#include <hip/hip_cooperative_groups.h>

namespace cg = cooperative_groups;

#define NIN 64
#define NOUT 32
#define TBITS 21                 // 128^3 stride-2 lattice
#define TSIZE (1 << TBITS)
#define NB 512                   // class-major: 8 classes x 64 spatial cells (64^3)
#define CHUNK 4096               // guides per chunk in count/scat
#define KPT (CHUNK / 256)
#define BLKG 128                 // guides per conv block-iter = 4 waves x 2 tiles x 16

typedef __attribute__((ext_vector_type(8))) short short8;
typedef __attribute__((ext_vector_type(4))) float float4v;
typedef __attribute__((ext_vector_type(4))) unsigned short ushort4v;

struct Args {
    const float* feats; const float* weights; const float* bias;
    const int* coords; const int* guide;
    float* out; int* wsI;
    int np, ng, fn4;
};

struct WS {
    int* table; int2* sorted; int* count; int* cursor; int* classbase;
    unsigned short* wt; unsigned short* fb; int n4;
};

__device__ __forceinline__ WS mkws(int* wsI, int ng) {
    WS w;
    int SC = (ng + 8 * BLKG + 3) & ~3;
    int A = TSIZE + 2 * SC;
    w.table = wsI;
    w.sorted = (int2*)(wsI + TSIZE);
    w.count = wsI + A;
    w.cursor = wsI + A + 512;
    w.classbase = wsI + A + 1024;
    w.wt = (unsigned short*)(wsI + A + 1040);
    w.fb = (unsigned short*)(wsI + A + 1040 + 27648);
    w.n4 = A / 4;
    return w;
}

__device__ __forceinline__ unsigned short bf16rne(float x) {
    unsigned u = __float_as_uint(x);
    u += 0x7fffu + ((u >> 16) & 1u);
    return (unsigned short)(u >> 16);
}

constexpr int popc8(int x) { int n = 0; for (int i = 0; i < 8; ++i) n += (x >> i) & 1; return n; }
constexpr int nth_sub(int C, int r) {
    int cnt = 0;
    for (int s = 0; s < 8; ++s)
        if ((s & ~C & 7) == 0) { if (cnt == r) return s; ++cnt; }
    return 0;
}

// class-major bucket: all guides of one parity class contiguous, spatially sorted
__device__ __forceinline__ int bucket_of(int4 q, int* cls) {
    int c = (q.y & 1) | ((q.z & 1) << 1) | ((q.w & 1) << 2);
    *cls = c;
    int sp = ((q.y >> 6) & 3) | (((q.z >> 6) & 3) << 2) | (((q.w >> 6) & 3) << 4);
    return (c << 6) | sp;
}

// ---------------- phases ----------------

// P0: init table+sorted to -1, zero count, wt convert, fb convert
__device__ void ph_init(const Args& a, const WS& w) {
    int gid = blockIdx.x * 256 + threadIdx.x;
    int tot = gridDim.x * 256;
    int4* ws4 = (int4*)a.wsI;
    for (int i = gid; i < w.n4; i += tot) ws4[i] = make_int4(-1, -1, -1, -1);
    int4* c4 = (int4*)w.count;
    for (int i = gid; i < NB / 4; i += tot) c4[i] = make_int4(0, 0, 0, 0);
    for (int i = gid; i < 27 * 64 * 32; i += tot) {
        int oi = i >> 11, k = (i >> 5) & 63, ch = i & 31;
        w.wt[oi * 2048 + ch * 64 + k] = bf16rne(a.weights[i]);
    }
    for (int i = gid; i < a.fn4; i += tot) {
        float4 v = ((const float4*)a.feats)[i];
        ushort4v o;
        o.x = bf16rne(v.x); o.y = bf16rne(v.y);
        o.z = bf16rne(v.z); o.w = bf16rne(v.w);
        ((ushort4v*)w.fb)[i] = o;
    }
}

// P1: table build + chunked LDS-histogram bucket count
__device__ void ph_count(const Args& a, const WS& w, int* hist) {
    int gid = blockIdx.x * 256 + threadIdx.x;
    int tot = gridDim.x * 256;
    for (int i = gid; i < a.np; i += tot) {
        int x = a.coords[i * 4 + 1];
        int y = a.coords[i * 4 + 2];
        int z = a.coords[i * 4 + 3];
        w.table[(x >> 1) | ((y >> 1) << 7) | ((z >> 1) << 14)] = i;
    }
    int cblocks = (a.ng + CHUNK - 1) / CHUNK;
    for (int ch = blockIdx.x; ch < cblocks; ch += gridDim.x) {
        for (int j = threadIdx.x; j < NB; j += 256) hist[j] = 0;
        __syncthreads();
        int base = ch * CHUNK;
        int end = base + CHUNK; if (end > a.ng) end = a.ng;
        for (int j = base + threadIdx.x; j < end; j += 256) {
            int c;
            int b = bucket_of(((const int4*)a.guide)[j], &c);
            atomicAdd(&hist[b], 1);
        }
        __syncthreads();
        for (int j = threadIdx.x; j < NB; j += 256)
            if (hist[j]) atomicAdd(&w.count[j], hist[j]);
        __syncthreads();
    }
}

// P2: scan 512 buckets on block 0 (256 threads, 2 buckets/thread);
// per-CLASS totals padded to BLKG; cursor = bucket base; classbase[9]
__device__ void ph_scan(const WS& w, int* smem) {
    if (blockIdx.x != 0) return;
    int t = threadIdx.x;
    int c0 = w.count[2 * t], c1 = w.count[2 * t + 1];
    int pair = c0 + c1;
    smem[t] = pair;
    __syncthreads();
    #pragma unroll
    for (int off = 1; off < 256; off <<= 1) {
        int v = smem[t];
        int u = (t >= off) ? smem[t - off] : 0;
        __syncthreads();
        smem[t] = v + u;
        __syncthreads();
    }
    int incl = smem[t];              // inclusive pair-sum through pair t
    int* cb = smem + 256;            // [9]
    if (t == 0) {
        int base = 0;
        #pragma unroll
        for (int cc = 0; cc < 8; ++cc) {
            cb[cc] = base;
            int hi = smem[cc * 32 + 31];
            int lo = cc ? smem[cc * 32 - 1] : 0;
            base += (hi - lo + BLKG - 1) & ~(BLKG - 1);
        }
        cb[8] = base;
        for (int j = 0; j < 9; ++j) w.classbase[j] = cb[j];
    }
    __syncthreads();
    int cc = t >> 5;                 // class of pair t (32 pairs per class)
    int lo = cc ? smem[cc * 32 - 1] : 0;
    int b0 = cb[cc] + (incl - pair) - lo;
    w.cursor[2 * t]     = b0;
    w.cursor[2 * t + 1] = b0 + c0;
}

// P3: chunked scatter; entry = {id | class<<24, x+1 | y+1<<9 | z+1<<18}
__device__ void ph_scat(const Args& a, const WS& w, int* hist) {
    int cblocks = (a.ng + CHUNK - 1) / CHUNK;
    int t = threadIdx.x;
    for (int ch = blockIdx.x; ch < cblocks; ch += gridDim.x) {
        for (int i = t; i < NB; i += 256) hist[i] = 0;
        __syncthreads();
        int base = ch * CHUNK;
        int packed[KPT];             // (bucket<<13) | lrank, or -1
        int ey[KPT];
        #pragma unroll
        for (int k = 0; k < KPT; ++k) {
            int i = base + k * 256 + t;
            packed[k] = -1;
            ey[k] = 0;
            if (i < a.ng) {
                int4 q = ((const int4*)a.guide)[i];
                int c;
                int b = bucket_of(q, &c);
                int lr = atomicAdd(&hist[b], 1);
                packed[k] = (b << 13) | lr;
                ey[k] = (q.y + 1) | ((q.z + 1) << 9) | ((q.w + 1) << 18);
            }
        }
        __syncthreads();
        for (int i = t; i < NB; i += 256) {
            int h = hist[i];
            hist[i] = h ? atomicAdd(&w.cursor[i], h) : 0;
        }
        __syncthreads();
        #pragma unroll
        for (int k = 0; k < KPT; ++k) {
            if (packed[k] >= 0) {
                int b  = packed[k] >> 13;
                int lr = packed[k] & 8191;
                int i  = base + k * 256 + t;
                int2 e;
                e.x = i | ((b >> 6) << 24);
                e.y = ey[k];
                w.sorted[hist[b] + lr] = e;
            }
        }
        __syncthreads();
    }
}

// ---------------- conv helpers (class templated, rank-compacted LDS) ----------------

template<int C>
__device__ __forceinline__ void probe2t(const int* __restrict__ table, int2 s2,
                                        int quad, int* o0, int* o1) {
    int qx = (s2.y & 511) - 1;
    int qy = ((s2.y >> 9) & 511) - 1;
    int qz = ((s2.y >> 18) & 511) - 1;
    int res[2];
    #pragma unroll
    for (int r = 0; r < 2; ++r) {
        int sub = quad + r * 4;
        int offx = (C & 1) ? ((sub & 1) ? 1 : -1) : 0;
        int offy = (C & 2) ? ((sub & 2) ? 1 : -1) : 0;
        int offz = (C & 4) ? ((sub & 4) ? 1 : -1) : 0;
        int px = qx - offx, py = qy - offy, pz = qz - offz;
        bool valid = (s2.x >= 0) & ((sub & ~C & 7) == 0) &
                     ((unsigned)px < 256u) & ((unsigned)py < 256u) & ((unsigned)pz < 256u);
        int lin = (px >> 1) | ((py >> 1) << 7) | ((pz >> 1) << 14);
        int v = table[valid ? lin : 0];
        res[r] = valid ? v : -1;
    }
    *o0 = res[0]; *o1 = res[1];
}

template<int C, int R, int NS>
__device__ __forceinline__ void stage_rank(const unsigned short* __restrict__ wt,
                                           unsigned short* bshr, int mm, int jj) {
    if constexpr (R < NS) {
        constexpr int SUB = nth_sub(C, R);
        constexpr int offx = (C & 1) ? ((SUB & 1) ? 1 : -1) : 0;
        constexpr int offy = (C & 2) ? ((SUB & 2) ? 1 : -1) : 0;
        constexpr int offz = (C & 4) ? ((SUB & 4) ? 1 : -1) : 0;
        constexpr int oi = (offx + 1) * 9 + (offy + 1) * 3 + (offz + 1);
        short8 v = *(const short8*)(wt + oi * 2048 + mm * 64 + jj * 8);
        *(short8*)((char*)bshr + (R & 3) * 4096 + mm * 128 + ((jj ^ (mm & 7)) << 4)) = v;
    }
}

template<int USEFB, int C, int R, int NS>
__device__ __forceinline__ void rank_load(const float* __restrict__ feats,
                                          const unsigned short* __restrict__ fb,
                                          int idx0, int idx1,
                                          unsigned long long bal0, unsigned long long bal1,
                                          int m, int quad, short8* A0, short8* A1) {
    if constexpr (R < NS) {
        constexpr int SUB = nth_sub(C, R);
        unsigned long long bal = (SUB < 4) ? bal0 : bal1;
        unsigned rowm = (unsigned)((bal >> ((SUB & 3) * 16)) & 0xffffull);
        short8 z = {0,0,0,0,0,0,0,0};
        A0[R & 3] = z; A1[R & 3] = z;
        if (rowm) {
            int h = __shfl((SUB < 4) ? idx0 : idx1, (SUB & 3) * 16 + m, 64);
            if (h >= 0) {
                if constexpr (USEFB) {
                    const unsigned short* fp = fb + (size_t)h * NIN + quad * 8;
                    A0[R & 3] = *(const short8*)fp;
                    A1[R & 3] = *(const short8*)(fp + 32);
                } else {
                    const float4* fp = (const float4*)(feats + (size_t)h * NIN + quad * 8);
                    float4 fA = fp[0], fB = fp[1];
                    const float4* fp2 = (const float4*)(feats + (size_t)h * NIN + 32 + quad * 8);
                    float4 fC = fp2[0], fD = fp2[1];
                    short8 x, y;
                    x[0] = (short)bf16rne(fA.x); x[1] = (short)bf16rne(fA.y);
                    x[2] = (short)bf16rne(fA.z); x[3] = (short)bf16rne(fA.w);
                    x[4] = (short)bf16rne(fB.x); x[5] = (short)bf16rne(fB.y);
                    x[6] = (short)bf16rne(fB.z); x[7] = (short)bf16rne(fB.w);
                    y[0] = (short)bf16rne(fC.x); y[1] = (short)bf16rne(fC.y);
                    y[2] = (short)bf16rne(fC.z); y[3] = (short)bf16rne(fC.w);
                    y[4] = (short)bf16rne(fD.x); y[5] = (short)bf16rne(fD.y);
                    y[6] = (short)bf16rne(fD.z); y[7] = (short)bf16rne(fD.w);
                    A0[R & 3] = x; A1[R & 3] = y;
                }
            }
        }
    }
}

template<int C, int R, int NS>
__device__ __forceinline__ void rank_mm(const unsigned short* bshr,
                                        unsigned long long bal0, unsigned long long bal1,
                                        int m, int quad, const short8* A0, const short8* A1,
                                        float4v* acc0, float4v* acc1) {
    if constexpr (R < NS) {
        constexpr int SUB = nth_sub(C, R);
        unsigned long long bal = (SUB < 4) ? bal0 : bal1;
        unsigned rowm = (unsigned)((bal >> ((SUB & 3) * 16)) & 0xffffull);
        if (rowm) {
            const char* base = (const char*)bshr + (R & 3) * 4096;
            short8 b00 = *(const short8*)(base + m * 128 + ((quad ^ (m & 7)) << 4));
            short8 b10 = *(const short8*)(base + m * 128 + (((4 + quad) ^ (m & 7)) << 4));
            short8 b01 = *(const short8*)(base + (16 + m) * 128 + ((quad ^ ((16 + m) & 7)) << 4));
            short8 b11 = *(const short8*)(base + (16 + m) * 128 + (((4 + quad) ^ ((16 + m) & 7)) << 4));
            *acc0 = __builtin_amdgcn_mfma_f32_16x16x32_bf16(A0[R & 3], b00, *acc0, 0, 0, 0);
            *acc0 = __builtin_amdgcn_mfma_f32_16x16x32_bf16(A1[R & 3], b10, *acc0, 0, 0, 0);
            *acc1 = __builtin_amdgcn_mfma_f32_16x16x32_bf16(A0[R & 3], b01, *acc1, 0, 0, 0);
            *acc1 = __builtin_amdgcn_mfma_f32_16x16x32_bf16(A1[R & 3], b11, *acc1, 0, 0, 0);
        }
    }
}

template<int USEFB, int C, int P>
__device__ __forceinline__ void phase_tile(const float* __restrict__ feats,
                                           const unsigned short* __restrict__ fb,
                                           const unsigned short* bshr,
                                           int idx0, int idx1,
                                           unsigned long long bal0, unsigned long long bal1,
                                           int m, int quad, float4v* acc0, float4v* acc1) {
    constexpr int NS = 1 << popc8(C);
    short8 A0[4], A1[4];
    rank_load<USEFB, C, P * 4 + 0, NS>(feats, fb, idx0, idx1, bal0, bal1, m, quad, A0, A1);
    rank_load<USEFB, C, P * 4 + 1, NS>(feats, fb, idx0, idx1, bal0, bal1, m, quad, A0, A1);
    rank_load<USEFB, C, P * 4 + 2, NS>(feats, fb, idx0, idx1, bal0, bal1, m, quad, A0, A1);
    rank_load<USEFB, C, P * 4 + 3, NS>(feats, fb, idx0, idx1, bal0, bal1, m, quad, A0, A1);
    rank_mm<C, P * 4 + 0, NS>(bshr, bal0, bal1, m, quad, A0, A1, acc0, acc1);
    rank_mm<C, P * 4 + 1, NS>(bshr, bal0, bal1, m, quad, A0, A1, acc0, acc1);
    rank_mm<C, P * 4 + 2, NS>(bshr, bal0, bal1, m, quad, A0, A1, acc0, acc1);
    rank_mm<C, P * 4 + 3, NS>(bshr, bal0, bal1, m, quad, A0, A1, acc0, acc1);
}

__device__ __forceinline__ void store_tile(int2 s2, unsigned long long eb,
                                           float4v acc0, float4v acc1,
                                           int m, int quad, float bv0, float bv1,
                                           float* __restrict__ out) {
    int id = (s2.x < 0) ? -1 : (s2.x & 0xffffff);
    unsigned e16 = (unsigned)((eb | (eb >> 16) | (eb >> 32) | (eb >> 48)) & 0xffffull);
    #pragma unroll
    for (int r = 0; r < 4; ++r) {
        int mr = quad * 4 + r;
        int idr = __shfl(id, mr, 64);
        if (idr >= 0) {
            bool exr = (e16 >> mr) & 1;
            out[(size_t)idr * NOUT + m]      = exr ? (acc0[r] + bv0) : 0.f;
            out[(size_t)idr * NOUT + 16 + m] = exr ? (acc1[r] + bv1) : 0.f;
        }
    }
}

template<int USEFB, int C>
__device__ __forceinline__ void conv_class(const float* __restrict__ feats,
                                           const unsigned short* __restrict__ fb,
                                           const float* __restrict__ bias,
                                           const int* __restrict__ table,
                                           const int2* __restrict__ sorted,
                                           const unsigned short* __restrict__ wt,
                                           float* __restrict__ out,
                                           int bt0, unsigned short* bshr) {
    constexpr int NS = 1 << popc8(C);
    int tid = threadIdx.x;
    int wid = tid >> 6, lane = tid & 63;
    int m = lane & 15, quad = lane >> 4;
    float bv0 = bias[m], bv1 = bias[16 + m];

    int t0 = bt0 + wid * 2;
    int2 s2a = sorted[t0 * 16 + m];
    int2 s2b = sorted[t0 * 16 + 16 + m];
    int ia0, ia1, ib0, ib1;
    probe2t<C>(table, s2a, quad, &ia0, &ia1);
    probe2t<C>(table, s2b, quad, &ib0, &ib1);

    {   // stage phase 0 (ranks 0..3) into 16 KB LDS
        int mm = tid >> 3, jj = tid & 7;
        stage_rank<C, 0, NS>(wt, bshr, mm, jj);
        stage_rank<C, 1, NS>(wt, bshr, mm, jj);
        stage_rank<C, 2, NS>(wt, bshr, mm, jj);
        stage_rank<C, 3, NS>(wt, bshr, mm, jj);
    }
    __syncthreads();

    unsigned long long balA0 = __ballot(ia0 >= 0), balA1 = __ballot(ia1 >= 0);
    unsigned long long balB0 = __ballot(ib0 >= 0), balB1 = __ballot(ib1 >= 0);

    float4v aA0 = {0.f,0.f,0.f,0.f}, aA1 = {0.f,0.f,0.f,0.f};
    float4v aB0 = {0.f,0.f,0.f,0.f}, aB1 = {0.f,0.f,0.f,0.f};

    phase_tile<USEFB, C, 0>(feats, fb, bshr, ia0, ia1, balA0, balA1, m, quad, &aA0, &aA1);
    phase_tile<USEFB, C, 0>(feats, fb, bshr, ib0, ib1, balB0, balB1, m, quad, &aB0, &aB1);

    if constexpr (NS > 4) {          // class 7 only: restage ranks 4..7
        __syncthreads();
        {
            int mm = tid >> 3, jj = tid & 7;
            stage_rank<C, 4, NS>(wt, bshr, mm, jj);
            stage_rank<C, 5, NS>(wt, bshr, mm, jj);
            stage_rank<C, 6, NS>(wt, bshr, mm, jj);
            stage_rank<C, 7, NS>(wt, bshr, mm, jj);
        }
        __syncthreads();
        phase_tile<USEFB, C, 1>(feats, fb, bshr, ia0, ia1, balA0, balA1, m, quad, &aA0, &aA1);
        phase_tile<USEFB, C, 1>(feats, fb, bshr, ib0, ib1, balB0, balB1, m, quad, &aB0, &aB1);
    }

    store_tile(s2a, balA0 | balA1, aA0, aA1, m, quad, bv0, bv1, out);
    store_tile(s2b, balB0 | balB1, aB0, aB1, m, quad, bv0, bv1, out);
}

// P4: grid-strided conv over BLKG groups, bijective XCD swizzle
template<int USEFB>
__device__ void ph_conv(const Args& a, const WS& w, unsigned short* bshr) {
    int total = w.classbase[8];          // BLKG-aligned
    int nwg = total / BLKG;
    int qd = nwg >> 3, rd = nwg & 7;
    for (int o = blockIdx.x; o < nwg; o += gridDim.x) {
        int xc = o & 7, ix = o >> 3;
        int wg = (xc < rd ? xc * (qd + 1) : rd * (qd + 1) + (xc - rd) * qd) + ix;
        int g0 = wg * BLKG;
        int c = 0;
        #pragma unroll
        for (int j = 1; j < 8; ++j) c += (g0 >= w.classbase[j]) ? 1 : 0;
        c = __builtin_amdgcn_readfirstlane(c);
        int bt0 = wg * (BLKG / 16);
        __syncthreads();                 // protect bshr from previous iteration's reads
        switch (c) {
            case 0: conv_class<USEFB, 0>(a.feats, w.fb, a.bias, w.table, w.sorted, w.wt, a.out, bt0, bshr); break;
            case 1: conv_class<USEFB, 1>(a.feats, w.fb, a.bias, w.table, w.sorted, w.wt, a.out, bt0, bshr); break;
            case 2: conv_class<USEFB, 2>(a.feats, w.fb, a.bias, w.table, w.sorted, w.wt, a.out, bt0, bshr); break;
            case 3: conv_class<USEFB, 3>(a.feats, w.fb, a.bias, w.table, w.sorted, w.wt, a.out, bt0, bshr); break;
            case 4: conv_class<USEFB, 4>(a.feats, w.fb, a.bias, w.table, w.sorted, w.wt, a.out, bt0, bshr); break;
            case 5: conv_class<USEFB, 5>(a.feats, w.fb, a.bias, w.table, w.sorted, w.wt, a.out, bt0, bshr); break;
            case 6: conv_class<USEFB, 6>(a.feats, w.fb, a.bias, w.table, w.sorted, w.wt, a.out, bt0, bshr); break;
            case 7: conv_class<USEFB, 7>(a.feats, w.fb, a.bias, w.table, w.sorted, w.wt, a.out, bt0, bshr); break;
        }
    }
}

// ---------------- kernels ----------------

template<int USEFB>
__launch_bounds__(256, 4)
__global__ void fused(Args a) {
    __shared__ int smem[4096];           // 16 KB, reused per phase
    WS w = mkws(a.wsI, a.ng);
    cg::grid_group g = cg::this_grid();
    ph_init(a, w);
    g.sync();
    ph_count(a, w, smem);
    g.sync();
    ph_scan(w, smem);
    g.sync();
    ph_scat(a, w, smem);
    g.sync();
    ph_conv<USEFB>(a, w, (unsigned short*)smem);
}

template<int USEFB>
__launch_bounds__(256, 4)
__global__ void fused_ph(Args a, int phase) {
    __shared__ int smem[4096];
    WS w = mkws(a.wsI, a.ng);
    if      (phase == 0) ph_init(a, w);
    else if (phase == 1) ph_count(a, w, smem);
    else if (phase == 2) ph_scan(w, smem);
    else if (phase == 3) ph_scat(a, w, smem);
    else                 ph_conv<USEFB>(a, w, (unsigned short*)smem);
}

extern "C" void kernel_launch(void* const* d_in, const int* in_sizes, int n_in,
                              void* d_out, int out_size, void* d_ws, size_t ws_size,
                              hipStream_t stream) {
    Args a;
    a.feats   = (const float*)d_in[0];
    a.weights = (const float*)d_in[1];
    a.bias    = (const float*)d_in[2];
    a.coords  = (const int*)d_in[3];
    a.guide   = (const int*)d_in[4];
    a.out     = (float*)d_out;
    a.wsI     = (int*)d_ws;
    a.np = in_sizes[3] / 4;
    a.ng = in_sizes[4] / 4;

    int SC = (a.ng + 8 * BLKG + 3) & ~3;
    int A = TSIZE + 2 * SC;
    size_t need = ((size_t)A + 1040 + 27648) * 4 + (size_t)a.np * NIN * 2;
    int usefb = (ws_size >= need) ? 1 : 0;
    a.fn4 = usefb ? a.np * (NIN / 4) : 0;

    // occupancy-bounded persistent grid for cooperative launch (MI355X: 256 CUs)
    static int occ1 = -1, occ0 = -1;
    int* occp = usefb ? &occ1 : &occ0;
    if (*occp < 0) {
        int nb = 0;
        hipError_t e = usefb
            ? hipOccupancyMaxActiveBlocksPerMultiprocessor(&nb, fused<1>, 256, 0)
            : hipOccupancyMaxActiveBlocksPerMultiprocessor(&nb, fused<0>, 256, 0);
        *occp = (e == hipSuccess && nb >= 1) ? nb : 2;
    }
    int grid = (*occp) * 256;
    if (grid > 4096) grid = 4096;

    void* params[] = { (void*)&a };
    hipError_t err = usefb
        ? hipLaunchCooperativeKernel((const void*)fused<1>, dim3(grid), dim3(256), params, 0, stream)
        : hipLaunchCooperativeKernel((const void*)fused<0>, dim3(grid), dim3(256), params, 0, stream);

    if (err != hipSuccess) {
        // fallback: 5 sequential dispatches (same behavior as previous round)
        int nwg_est = (a.ng + 8 * (BLKG - 1) + BLKG - 1) / BLKG;
        for (int ph = 0; ph < 5; ++ph) {
            int g = (ph == 2) ? 1 : ((ph == 4) ? nwg_est : 2048);
            if (usefb) {
                hipLaunchKernelGGL((fused_ph<1>), dim3(g), dim3(256), 0, stream, a, ph);
            } else {
                hipLaunchKernelGGL((fused_ph<0>), dim3(g), dim3(256), 0, stream, a, ph);
            }
        }
    }
}

// Round 9
// 170.790 us; speedup vs baseline: 2.6477x; 2.6477x over previous
//
#include <hip/hip_runtime.h>

#define NIN 64
#define NOUT 32
#define TBITS 21                 // 128^3 stride-2 lattice
#define TSIZE (1 << TBITS)
#define NB 512                   // class-major: 8 classes x 64 spatial cells (64^3)
#define CHUNK 4096               // guides per block in prep-count/scat
#define KPT (CHUNK / 256)
#define BLKG 128                 // guides per gen_conv block = 4 waves x 2 tiles x 16

typedef __attribute__((ext_vector_type(8))) short short8;
typedef __attribute__((ext_vector_type(4))) float float4v;
typedef __attribute__((ext_vector_type(4))) unsigned short ushort4v;

__device__ __forceinline__ unsigned short bf16rne(float x) {
    unsigned u = __float_as_uint(x);
    u += 0x7fffu + ((u >> 16) & 1u);
    return (unsigned short)(u >> 16);
}

constexpr int popc8(int x) { int n = 0; for (int i = 0; i < 8; ++i) n += (x >> i) & 1; return n; }
constexpr int nth_sub(int C, int r) {
    int cnt = 0;
    for (int s = 0; s < 8; ++s)
        if ((s & ~C & 7) == 0) { if (cnt == r) return s; ++cnt; }
    return 0;
}

// class-major bucket: all guides of one parity class contiguous, spatially sorted
__device__ __forceinline__ int bucket_of(int4 q, int* cls) {
    int c = (q.y & 1) | ((q.z & 1) << 1) | ((q.w & 1) << 2);
    *cls = c;
    int sp = ((q.y >> 6) & 3) | (((q.z >> 6) & 3) << 2) | (((q.w >> 6) & 3) << 4);
    return (c << 6) | sp;
}

// ws (ints): [0,TSIZE) table | [TSIZE, A) sorted int2 (-1 padded) |
//   A: count[512] | cursor[512] at A+512 | classbase[16] at A+1024 |
//   wt bf16 [27][32][64] at A+1040 | fb bf16 [Np][64] after wt
// prep: init table+sorted, wt/fb convert, bucket count (count[] pre-zeroed by memset)
__global__ void prep(int4* __restrict__ ws4, int n4,
                     const float* __restrict__ w, unsigned short* __restrict__ wt,
                     const float* __restrict__ f, unsigned short* __restrict__ fb,
                     int fn4,
                     const int* __restrict__ guide, int ng, int* __restrict__ count) {
    __shared__ int hist[NB];
    int i = blockIdx.x * blockDim.x + threadIdx.x;
    if (i < n4) ws4[i] = make_int4(-1, -1, -1, -1);
    if (i < 27 * 64 * 32) {          // fp32 [27][64][32] -> bf16 [27][32][64]
        int oi = i >> 11;
        int k  = (i >> 5) & 63;
        int ch = i & 31;
        wt[oi * 2048 + ch * 64 + k] = bf16rne(w[i]);
    }
    if (i < fn4) {
        float4 v = ((const float4*)f)[i];
        ushort4v o;
        o.x = bf16rne(v.x); o.y = bf16rne(v.y);
        o.z = bf16rne(v.z); o.w = bf16rne(v.w);
        ((ushort4v*)fb)[i] = o;
    }
    int base = blockIdx.x * CHUNK;
    if (base < ng) {
        for (int j = threadIdx.x; j < NB; j += 256) hist[j] = 0;
        __syncthreads();
        int end = base + CHUNK; if (end > ng) end = ng;
        for (int j = base + threadIdx.x; j < end; j += 256) {
            int c;
            int b = bucket_of(((const int4*)guide)[j], &c);
            atomicAdd(&hist[b], 1);
        }
        __syncthreads();
        for (int j = threadIdx.x; j < NB; j += 256)
            if (hist[j]) atomicAdd(&count[j], hist[j]);
    }
}

// scan over 512 class-major buckets; per-CLASS totals padded to BLKG so every
// gen_conv block is class-uniform. cursor = bucket write base; classbase[9].
__global__ void scanB(const int* __restrict__ count, int* __restrict__ cursor,
                      int* __restrict__ classbase) {
    __shared__ int ps[512];
    __shared__ int cb[9];
    int t = threadIdx.x;
    int v = count[t];
    ps[t] = v;
    __syncthreads();
    #pragma unroll
    for (int off = 1; off < 512; off <<= 1) {
        int val = ps[t];
        int u = (t >= off) ? ps[t - off] : 0;
        __syncthreads();
        ps[t] = val + u;
        __syncthreads();
    }
    int incl = ps[t];
    if (t == 0) {
        int base = 0;
        #pragma unroll
        for (int cc = 0; cc < 8; ++cc) {
            cb[cc] = base;
            int hi = ps[cc * 64 + 63];
            int lo = cc ? ps[cc * 64 - 1] : 0;
            base += (hi - lo + BLKG - 1) & ~(BLKG - 1);
        }
        cb[8] = base;
        for (int j = 0; j < 9; ++j) classbase[j] = cb[j];
    }
    __syncthreads();
    int cc = t >> 6;
    int lo = cc ? ps[cc * 64 - 1] : 0;
    cursor[t] = cb[cc] + (incl - v) - lo;
}

// table build + chunked scatter; entry = {id | class<<24, x+1 | y+1<<9 | z+1<<18}
__global__ void scat(const int* __restrict__ coords, int np, int* __restrict__ table,
                     const int* __restrict__ guide, int ng,
                     int* __restrict__ cursor, int2* __restrict__ sorted) {
    int gi = blockIdx.x * blockDim.x + threadIdx.x;
    if (gi < np) {
        int x = coords[gi * 4 + 1];
        int y = coords[gi * 4 + 2];
        int z = coords[gi * 4 + 3];
        table[(x >> 1) | ((y >> 1) << 7) | ((z >> 1) << 14)] = gi;
    }
    __shared__ int hist[NB];
    int t = threadIdx.x;
    int base = blockIdx.x * CHUNK;
    if (base >= ng) return;
    for (int i = t; i < NB; i += 256) hist[i] = 0;
    __syncthreads();
    int packed[KPT];                 // (bucket<<13) | lrank, or -1
    int ey[KPT];
    #pragma unroll
    for (int k = 0; k < KPT; ++k) {
        int i = base + k * 256 + t;
        packed[k] = -1;
        ey[k] = 0;
        if (i < ng) {
            int4 q = ((const int4*)guide)[i];
            int c;
            int b = bucket_of(q, &c);
            int lr = atomicAdd(&hist[b], 1);
            packed[k] = (b << 13) | lr;
            ey[k] = (q.y + 1) | ((q.z + 1) << 9) | ((q.w + 1) << 18);
        }
    }
    __syncthreads();
    for (int i = t; i < NB; i += 256) {
        int h = hist[i];
        hist[i] = h ? atomicAdd(&cursor[i], h) : 0;
    }
    __syncthreads();
    #pragma unroll
    for (int k = 0; k < KPT; ++k) {
        if (packed[k] >= 0) {
            int b  = packed[k] >> 13;
            int lr = packed[k] & 8191;
            int i  = base + k * 256 + t;
            int2 e;
            e.x = i | ((b >> 6) << 24);     // class = bucket>>6 (class-major)
            e.y = ey[k];
            sorted[hist[b] + lr] = e;
        }
    }
}

// ---------------- gen_conv helpers (class templated, rank-compacted LDS) ----------------

template<int C>
__device__ __forceinline__ void probe2t(const int* __restrict__ table, int2 s2,
                                        int quad, int* o0, int* o1) {
    int qx = (s2.y & 511) - 1;
    int qy = ((s2.y >> 9) & 511) - 1;
    int qz = ((s2.y >> 18) & 511) - 1;
    int res[2];
    #pragma unroll
    for (int r = 0; r < 2; ++r) {
        int sub = quad + r * 4;
        int offx = (C & 1) ? ((sub & 1) ? 1 : -1) : 0;
        int offy = (C & 2) ? ((sub & 2) ? 1 : -1) : 0;
        int offz = (C & 4) ? ((sub & 4) ? 1 : -1) : 0;
        int px = qx - offx, py = qy - offy, pz = qz - offz;
        bool valid = (s2.x >= 0) & ((sub & ~C & 7) == 0) &
                     ((unsigned)px < 256u) & ((unsigned)py < 256u) & ((unsigned)pz < 256u);
        int lin = (px >> 1) | ((py >> 1) << 7) | ((pz >> 1) << 14);
        int v = table[valid ? lin : 0];
        res[r] = valid ? v : -1;
    }
    *o0 = res[0]; *o1 = res[1];
}

// stage wt[oi] for admissible rank R into LDS slot (R&3), XOR swizzled
template<int C, int R, int NS>
__device__ __forceinline__ void stage_rank(const unsigned short* __restrict__ wt,
                                           unsigned short* bshr, int mm, int jj) {
    if constexpr (R < NS) {
        constexpr int SUB = nth_sub(C, R);
        constexpr int offx = (C & 1) ? ((SUB & 1) ? 1 : -1) : 0;
        constexpr int offy = (C & 2) ? ((SUB & 2) ? 1 : -1) : 0;
        constexpr int offz = (C & 4) ? ((SUB & 4) ? 1 : -1) : 0;
        constexpr int oi = (offx + 1) * 9 + (offy + 1) * 3 + (offz + 1);
        short8 v = *(const short8*)(wt + oi * 2048 + mm * 64 + jj * 8);
        *(short8*)((char*)bshr + (R & 3) * 4096 + mm * 128 + ((jj ^ (mm & 7)) << 4)) = v;
    }
}

template<int USEFB, int C, int R, int NS>
__device__ __forceinline__ void rank_load(const float* __restrict__ feats,
                                          const unsigned short* __restrict__ fb,
                                          int idx0, int idx1,
                                          unsigned long long bal0, unsigned long long bal1,
                                          int m, int quad, short8* A0, short8* A1) {
    if constexpr (R < NS) {
        constexpr int SUB = nth_sub(C, R);
        unsigned long long bal = (SUB < 4) ? bal0 : bal1;
        unsigned rowm = (unsigned)((bal >> ((SUB & 3) * 16)) & 0xffffull);
        short8 z = {0,0,0,0,0,0,0,0};
        A0[R & 3] = z; A1[R & 3] = z;
        if (rowm) {
            int h = __shfl((SUB < 4) ? idx0 : idx1, (SUB & 3) * 16 + m, 64);
            if (h >= 0) {
                if constexpr (USEFB) {
                    const unsigned short* fp = fb + (size_t)h * NIN + quad * 8;
                    A0[R & 3] = *(const short8*)fp;
                    A1[R & 3] = *(const short8*)(fp + 32);
                } else {
                    const float4* fp = (const float4*)(feats + (size_t)h * NIN + quad * 8);
                    float4 fA = fp[0], fB = fp[1];
                    const float4* fp2 = (const float4*)(feats + (size_t)h * NIN + 32 + quad * 8);
                    float4 fC = fp2[0], fD = fp2[1];
                    short8 x, y;
                    x[0] = (short)bf16rne(fA.x); x[1] = (short)bf16rne(fA.y);
                    x[2] = (short)bf16rne(fA.z); x[3] = (short)bf16rne(fA.w);
                    x[4] = (short)bf16rne(fB.x); x[5] = (short)bf16rne(fB.y);
                    x[6] = (short)bf16rne(fB.z); x[7] = (short)bf16rne(fB.w);
                    y[0] = (short)bf16rne(fC.x); y[1] = (short)bf16rne(fC.y);
                    y[2] = (short)bf16rne(fC.z); y[3] = (short)bf16rne(fC.w);
                    y[4] = (short)bf16rne(fD.x); y[5] = (short)bf16rne(fD.y);
                    y[6] = (short)bf16rne(fD.z); y[7] = (short)bf16rne(fD.w);
                    A0[R & 3] = x; A1[R & 3] = y;
                }
            }
        }
    }
}

// OPERAND-SWAPPED: mfma(W_frag, F_frag) -> acc holds out[g_m][4 consecutive ch].
// Same fragments, same lanes; only the roles differ.
template<int C, int R, int NS>
__device__ __forceinline__ void rank_mm(const unsigned short* bshr,
                                        unsigned long long bal0, unsigned long long bal1,
                                        int m, int quad, const short8* A0, const short8* A1,
                                        float4v* acc0, float4v* acc1) {
    if constexpr (R < NS) {
        constexpr int SUB = nth_sub(C, R);
        unsigned long long bal = (SUB < 4) ? bal0 : bal1;
        unsigned rowm = (unsigned)((bal >> ((SUB & 3) * 16)) & 0xffffull);
        if (rowm) {
            const char* base = (const char*)bshr + (R & 3) * 4096;
            short8 b00 = *(const short8*)(base + m * 128 + ((quad ^ (m & 7)) << 4));
            short8 b10 = *(const short8*)(base + m * 128 + (((4 + quad) ^ (m & 7)) << 4));
            short8 b01 = *(const short8*)(base + (16 + m) * 128 + ((quad ^ ((16 + m) & 7)) << 4));
            short8 b11 = *(const short8*)(base + (16 + m) * 128 + (((4 + quad) ^ ((16 + m) & 7)) << 4));
            *acc0 = __builtin_amdgcn_mfma_f32_16x16x32_bf16(b00, A0[R & 3], *acc0, 0, 0, 0);
            *acc0 = __builtin_amdgcn_mfma_f32_16x16x32_bf16(b10, A1[R & 3], *acc0, 0, 0, 0);
            *acc1 = __builtin_amdgcn_mfma_f32_16x16x32_bf16(b01, A0[R & 3], *acc1, 0, 0, 0);
            *acc1 = __builtin_amdgcn_mfma_f32_16x16x32_bf16(b11, A1[R & 3], *acc1, 0, 0, 0);
        }
    }
}

template<int USEFB, int C, int P>
__device__ __forceinline__ void phase_tile(const float* __restrict__ feats,
                                           const unsigned short* __restrict__ fb,
                                           const unsigned short* bshr,
                                           int idx0, int idx1,
                                           unsigned long long bal0, unsigned long long bal1,
                                           int m, int quad, float4v* acc0, float4v* acc1) {
    constexpr int NS = 1 << popc8(C);
    short8 A0[4], A1[4];
    rank_load<USEFB, C, P * 4 + 0, NS>(feats, fb, idx0, idx1, bal0, bal1, m, quad, A0, A1);
    rank_load<USEFB, C, P * 4 + 1, NS>(feats, fb, idx0, idx1, bal0, bal1, m, quad, A0, A1);
    rank_load<USEFB, C, P * 4 + 2, NS>(feats, fb, idx0, idx1, bal0, bal1, m, quad, A0, A1);
    rank_load<USEFB, C, P * 4 + 3, NS>(feats, fb, idx0, idx1, bal0, bal1, m, quad, A0, A1);
    rank_mm<C, P * 4 + 0, NS>(bshr, bal0, bal1, m, quad, A0, A1, acc0, acc1);
    rank_mm<C, P * 4 + 1, NS>(bshr, bal0, bal1, m, quad, A0, A1, acc0, acc1);
    rank_mm<C, P * 4 + 2, NS>(bshr, bal0, bal1, m, quad, A0, A1, acc0, acc1);
    rank_mm<C, P * 4 + 3, NS>(bshr, bal0, bal1, m, quad, A0, A1, acc0, acc1);
}

// lane (quad,m): acc0 = out[g_m][quad*4 .. +3], acc1 = out[g_m][16+quad*4 .. +3]
// -> two dwordx4 stores per tile, no shfl
__device__ __forceinline__ void store_tile(int2 s2, unsigned long long eb,
                                           float4v acc0, float4v acc1,
                                           int m, int quad, const float* __restrict__ bias,
                                           float* __restrict__ out) {
    int id = (s2.x < 0) ? -1 : (s2.x & 0xffffff);
    if (id < 0) return;
    unsigned e16 = (unsigned)((eb | (eb >> 16) | (eb >> 32) | (eb >> 48)) & 0xffffull);
    bool ex = (e16 >> m) & 1;
    float4 b0 = ((const float4*)bias)[quad];
    float4 b1 = ((const float4*)bias)[4 + quad];
    float4v v0, v1;
    v0[0] = ex ? (acc0[0] + b0.x) : 0.f;
    v0[1] = ex ? (acc0[1] + b0.y) : 0.f;
    v0[2] = ex ? (acc0[2] + b0.z) : 0.f;
    v0[3] = ex ? (acc0[3] + b0.w) : 0.f;
    v1[0] = ex ? (acc1[0] + b1.x) : 0.f;
    v1[1] = ex ? (acc1[1] + b1.y) : 0.f;
    v1[2] = ex ? (acc1[2] + b1.z) : 0.f;
    v1[3] = ex ? (acc1[3] + b1.w) : 0.f;
    float* op = out + (size_t)id * NOUT;
    *(float4v*)(op + quad * 4)      = v0;
    *(float4v*)(op + 16 + quad * 4) = v1;
}

template<int USEFB, int C>
__device__ __forceinline__ void conv_class(const float* __restrict__ feats,
                                           const unsigned short* __restrict__ fb,
                                           const float* __restrict__ bias,
                                           const int* __restrict__ table,
                                           const int2* __restrict__ sorted,
                                           const unsigned short* __restrict__ wt,
                                           float* __restrict__ out,
                                           int bt0, unsigned short* bshr) {
    constexpr int NS = 1 << popc8(C);
    int tid = threadIdx.x;
    int wid = tid >> 6, lane = tid & 63;
    int m = lane & 15, quad = lane >> 4;

    int t0 = bt0 + wid * 2;
    // both tiles' metadata + probes issued upfront (max loads in flight)
    int2 s2a = sorted[t0 * 16 + m];
    int2 s2b = sorted[t0 * 16 + 16 + m];
    int ia0, ia1, ib0, ib1;
    probe2t<C>(table, s2a, quad, &ia0, &ia1);
    probe2t<C>(table, s2b, quad, &ib0, &ib1);

    {   // stage phase 0 (ranks 0..3) into 16 KB LDS
        int mm = tid >> 3, jj = tid & 7;
        stage_rank<C, 0, NS>(wt, bshr, mm, jj);
        stage_rank<C, 1, NS>(wt, bshr, mm, jj);
        stage_rank<C, 2, NS>(wt, bshr, mm, jj);
        stage_rank<C, 3, NS>(wt, bshr, mm, jj);
    }
    __syncthreads();

    unsigned long long balA0 = __ballot(ia0 >= 0), balA1 = __ballot(ia1 >= 0);
    unsigned long long balB0 = __ballot(ib0 >= 0), balB1 = __ballot(ib1 >= 0);

    float4v aA0 = {0.f,0.f,0.f,0.f}, aA1 = {0.f,0.f,0.f,0.f};
    float4v aB0 = {0.f,0.f,0.f,0.f}, aB1 = {0.f,0.f,0.f,0.f};

    phase_tile<USEFB, C, 0>(feats, fb, bshr, ia0, ia1, balA0, balA1, m, quad, &aA0, &aA1);
    phase_tile<USEFB, C, 0>(feats, fb, bshr, ib0, ib1, balB0, balB1, m, quad, &aB0, &aB1);

    if constexpr (NS > 4) {          // class 7 only: restage ranks 4..7
        __syncthreads();
        {
            int mm = tid >> 3, jj = tid & 7;
            stage_rank<C, 4, NS>(wt, bshr, mm, jj);
            stage_rank<C, 5, NS>(wt, bshr, mm, jj);
            stage_rank<C, 6, NS>(wt, bshr, mm, jj);
            stage_rank<C, 7, NS>(wt, bshr, mm, jj);
        }
        __syncthreads();
        phase_tile<USEFB, C, 1>(feats, fb, bshr, ia0, ia1, balA0, balA1, m, quad, &aA0, &aA1);
        phase_tile<USEFB, C, 1>(feats, fb, bshr, ib0, ib1, balB0, balB1, m, quad, &aB0, &aB1);
    }

    store_tile(s2a, balA0 | balA1, aA0, aA1, m, quad, bias, out);
    store_tile(s2b, balB0 | balB1, aB0, aB1, m, quad, bias, out);
}

template<int USEFB>
__launch_bounds__(256, 6)
__global__ void gen_conv(const float* __restrict__ feats,
                         const unsigned short* __restrict__ fb,
                         const float* __restrict__ bias,
                         const int* __restrict__ table,
                         const int2* __restrict__ sorted,
                         const int* __restrict__ classbase,   // [9], BLKG-aligned
                         const unsigned short* __restrict__ wt,
                         float* __restrict__ out) {
    __shared__ unsigned short bshr[8192];                      // 16 KB

    int nwg = gridDim.x;
    int orig = blockIdx.x;
    int qd = nwg >> 3, rd = nwg & 7;
    int xc = orig & 7, ix = orig >> 3;
    int wg = (xc < rd ? xc * (qd + 1) : rd * (qd + 1) + (xc - rd) * qd) + ix;

    int g0 = wg * BLKG;
    if (g0 >= classbase[8]) return;     // uniform exit
    int c = 0;
    #pragma unroll
    for (int j = 1; j < 8; ++j) c += (g0 >= classbase[j]) ? 1 : 0;
    c = __builtin_amdgcn_readfirstlane(c);
    int bt0 = wg * (BLKG / 16);

    switch (c) {
        case 0: conv_class<USEFB, 0>(feats, fb, bias, table, sorted, wt, out, bt0, bshr); break;
        case 1: conv_class<USEFB, 1>(feats, fb, bias, table, sorted, wt, out, bt0, bshr); break;
        case 2: conv_class<USEFB, 2>(feats, fb, bias, table, sorted, wt, out, bt0, bshr); break;
        case 3: conv_class<USEFB, 3>(feats, fb, bias, table, sorted, wt, out, bt0, bshr); break;
        case 4: conv_class<USEFB, 4>(feats, fb, bias, table, sorted, wt, out, bt0, bshr); break;
        case 5: conv_class<USEFB, 5>(feats, fb, bias, table, sorted, wt, out, bt0, bshr); break;
        case 6: conv_class<USEFB, 6>(feats, fb, bias, table, sorted, wt, out, bt0, bshr); break;
        case 7: conv_class<USEFB, 7>(feats, fb, bias, table, sorted, wt, out, bt0, bshr); break;
    }
}

extern "C" void kernel_launch(void* const* d_in, const int* in_sizes, int n_in,
                              void* d_out, int out_size, void* d_ws, size_t ws_size,
                              hipStream_t stream) {
    const float* feats   = (const float*)d_in[0];
    const float* weights = (const float*)d_in[1];
    const float* bias    = (const float*)d_in[2];
    const int*   coords  = (const int*)d_in[3];
    const int*   guide   = (const int*)d_in[4];
    float* out = (float*)d_out;

    int np = in_sizes[3] / 4;
    int ng = in_sizes[4] / 4;

    int* wsI = (int*)d_ws;
    int SC = (ng + 8 * BLKG + 3) & ~3;       // sorted capacity (entries)
    int A = TSIZE + 2 * SC;                  // sorted is int2
    int* table     = wsI;                    // 2^21
    int2* sorted   = (int2*)(wsI + TSIZE);   // SC entries, -1 padded
    int* count     = wsI + A;                // 512
    int* cursor    = wsI + A + 512;          // 512
    int* classbase = wsI + A + 1024;         // 9 (+pad to 16)
    unsigned short* wt = (unsigned short*)(wsI + A + 1040);   // 27*32*64 bf16
    unsigned short* fb = (unsigned short*)(wsI + A + 1040 + 27648);
    size_t need = ((size_t)A + 1040 + 27648) * 4 + (size_t)np * NIN * 2;
    int usefb = (ws_size >= need) ? 1 : 0;

    hipMemsetAsync(count, 0, NB * sizeof(int), stream);

    int n4 = A / 4;
    int fn4 = usefb ? np * (NIN / 4) : 0;
    int prep_n = n4 > fn4 ? n4 : fn4;
    if (prep_n < 27 * 64 * 32) prep_n = 27 * 64 * 32;
    int prep_blocks = (prep_n + 255) / 256;
    int cblocks = (ng + CHUNK - 1) / CHUNK;
    if (prep_blocks < cblocks) prep_blocks = cblocks;
    hipLaunchKernelGGL(prep, dim3(prep_blocks), dim3(256), 0, stream,
                       (int4*)wsI, n4, weights, wt, feats, fb, fn4, guide, ng, count);

    hipLaunchKernelGGL(scanB, dim3(1), dim3(512), 0, stream, count, cursor, classbase);

    int sb1 = (np + 255) / 256;
    int sblocks = sb1 > cblocks ? sb1 : cblocks;
    hipLaunchKernelGGL(scat, dim3(sblocks), dim3(256), 0, stream,
                       coords, np, table, guide, ng, cursor, sorted);

    int maxguides = ng + 8 * (BLKG - 1);
    int blocks = (maxguides + BLKG - 1) / BLKG;
    if (usefb) {
        hipLaunchKernelGGL((gen_conv<1>), dim3(blocks), dim3(256), 0, stream,
                           feats, fb, bias, table, sorted, classbase, wt, out);
    } else {
        hipLaunchKernelGGL((gen_conv<0>), dim3(blocks), dim3(256), 0, stream,
                           feats, fb, bias, table, sorted, classbase, wt, out);
    }
}